// Round 1
// baseline (1164.334 us; speedup 1.0000x reference)
//
#include <hip/hip_runtime.h>
#include <cstddef>

// Problem constants
#define B_   128
#define V_   512
#define DIN_ 511
#define DOUT_ 256
#define DEPTH_ 8

// ---------------- kernel 1: softmax of L rows -> W ----------------
__global__ void k_softmax(const float* __restrict__ L, float* __restrict__ W) {
    const int i = blockIdx.x;       // step
    const int t = threadIdx.x;      // 256 threads
    __shared__ float red[256];
    float x0 = L[i * V_ + t];
    float x1 = L[i * V_ + 256 + t];
    float m = fmaxf(x0, x1);
    red[t] = m; __syncthreads();
    for (int s = 128; s > 0; s >>= 1) {
        if (t < s) red[t] = fmaxf(red[t], red[t + s]);
        __syncthreads();
    }
    const float mx = red[0];
    __syncthreads();
    float e0 = expf(x0 - mx), e1 = expf(x1 - mx);
    red[t] = e0 + e1; __syncthreads();
    for (int s = 128; s > 0; s >>= 1) {
        if (t < s) red[t] += red[t + s];
        __syncthreads();
    }
    const float inv = 1.0f / red[0];
    W[i * V_ + t]       = e0 * inv;
    W[i * V_ + 256 + t] = e1 * inv;
}

// ---------------- kernel 2: baseH[i] = W[i]@vu, baseF[i] = W[i]@vfs ----------------
// grid = DEPTH*3 blocks, 256 threads. part 0/1: H columns, part 2: F columns.
__global__ void k_base(const float* __restrict__ W, const float* __restrict__ vu,
                       const float* __restrict__ vfs,
                       float* __restrict__ baseH, float* __restrict__ baseF) {
    const int bx = blockIdx.x;
    const int i = bx / 3, part = bx % 3;
    const int t = threadIdx.x;
    __shared__ float Wl[V_];
    Wl[t] = W[i * V_ + t];
    Wl[t + 256] = W[i * V_ + 256 + t];
    __syncthreads();
    if (part < 2) {
        int d = part * 256 + t;
        if (d < DIN_) {
            float acc = 0.0f;
            for (int v = 0; v < V_; ++v) acc += Wl[v] * vu[v * DIN_ + d];
            baseH[i * DIN_ + d] = acc;
        }
    } else {
        int o = t;
        float acc = 0.0f;
        for (int v = 0; v < V_; ++v) acc += Wl[v] * vfs[v * DOUT_ + o];
        baseF[i * DOUT_ + o] = acc;
    }
}

// ---------------- kernel 3: sequential scan, one block per batch row ----------------
__global__ void __launch_bounds__(256)
k_scan(const float* __restrict__ inp, const float* __restrict__ vu,
       const float* __restrict__ vfs, const float* __restrict__ biases,
       const float* __restrict__ W, const float* __restrict__ baseH,
       const float* __restrict__ baseF,
       float* __restrict__ out, float* __restrict__ sel, float* __restrict__ lasth,
       int* __restrict__ idxh_g) {
    const int b = blockIdx.x;
    const int t = threadIdx.x;   // 256 threads

    __shared__ float iw[V_];
    __shared__ float Wl[V_];
    __shared__ float selh[DEPTH_][DIN_];
    __shared__ float fvals[DEPTH_][DOUT_];
    __shared__ float redv[256];
    __shared__ int   redi[256];
    __shared__ int   idxh[DEPTH_];

    // ---- build iw0 = [1 - sum(inp[b]), inp[b]] ----
    float x0 = inp[b * DIN_ + t];
    float x1 = (t < 255) ? inp[b * DIN_ + 256 + t] : 0.0f;
    redv[t] = x0 + x1; __syncthreads();
    for (int s = 128; s > 0; s >>= 1) {
        if (t < s) redv[t] += redv[t + s];
        __syncthreads();
    }
    if (t == 0) iw[0] = 1.0f - redv[0];
    iw[t + 1] = x0;                 // v = 1..256
    if (t < 255) iw[t + 257] = x1;  // v = 257..511
    __syncthreads();

    // ---- scan over DEPTH steps ----
    for (int i = 0; i < DEPTH_; ++i) {
        Wl[t] = W[i * V_ + t];
        Wl[t + 256] = W[i * V_ + 256 + t];
        __syncthreads();

        // argmin of iw / (w + 1e-20), first-index tie-break
        float d0 = iw[t]       / (Wl[t]       + 1e-20f);
        float d1 = iw[t + 256] / (Wl[t + 256] + 1e-20f);
        float bv; int bi;
        if (d0 <= d1) { bv = d0; bi = t; } else { bv = d1; bi = t + 256; }
        redv[t] = bv; redi[t] = bi; __syncthreads();
        for (int s = 128; s > 0; s >>= 1) {
            if (t < s) {
                float ov = redv[t + s]; int oi = redi[t + s];
                if (ov < redv[t] || (ov == redv[t] && oi < redi[t])) {
                    redv[t] = ov; redi[t] = oi;
                }
            }
            __syncthreads();
        }
        const float mval = redv[0];
        const int   midx = redi[0];
        __syncthreads();

        // iw update: iw -= mval * w  (all v), then iw[midx] = mval
        iw[t]       -= mval * Wl[t];
        iw[t + 256] -= mval * Wl[t + 256];
        __syncthreads();
        if (t == 0) { iw[midx] = mval; idxh[i] = midx; }
        __syncthreads();

        // new_h = baseH[i] + corrections over live replaced rows (j < i)
        for (int d = t; d < DIN_; d += 256) {
            float acc = baseH[i * DIN_ + d];
            for (int j = 0; j < i; ++j) {
                int r = idxh[j];
                bool alive = true;
                for (int j2 = j + 1; j2 < i; ++j2)
                    if (idxh[j2] == r) { alive = false; break; }
                if (alive) acc += Wl[r] * (selh[j][d] - vu[r * DIN_ + d]);
            }
            selh[i][d] = acc;
            sel[(size_t)(i * B_ + b) * DIN_ + d] = acc;
        }
        // new_f = baseF[i] + bias[i] + corrections
        {
            int o = t;
            float acc = baseF[i * DOUT_ + o] + biases[i * DOUT_ + o];
            for (int j = 0; j < i; ++j) {
                int r = idxh[j];
                bool alive = true;
                for (int j2 = j + 1; j2 < i; ++j2)
                    if (idxh[j2] == r) { alive = false; break; }
                if (alive) acc += Wl[r] * (fvals[j][o] - vfs[r * DOUT_ + o]);
            }
            fvals[i][o] = acc;
        }
        __syncthreads();
    }

    // ---- final out[b] = iw_final . f_final ----
    {
        int o = t;
        float acc = 0.0f;
        for (int v = 0; v < V_; ++v) acc += iw[v] * vfs[v * DOUT_ + o];
        for (int j = 0; j < DEPTH_; ++j) {
            int r = idxh[j];
            bool alive = true;
            for (int j2 = j + 1; j2 < DEPTH_; ++j2)
                if (idxh[j2] == r) { alive = false; break; }
            if (alive) acc += iw[r] * (fvals[j][o] - vfs[r * DOUT_ + o]);
        }
        out[b * DOUT_ + o] = acc;
    }
    // last_h = selh[DEPTH-1]
    for (int d = t; d < DIN_; d += 256)
        lasth[b * DIN_ + d] = selh[DEPTH_ - 1][d];
    // export idx history
    if (t < DEPTH_) idxh_g[b * DEPTH_ + t] = idxh[t];
}

// ---------------- kernel 4: bulk plane copy vu -> h_old_stack ----------------
// 1 plane = V_*DIN_ = 261632 floats = 65408 float4 (16B-divisible). grid = 1024*4.
__global__ void k_planes(const float* __restrict__ vu, float* __restrict__ hold) {
    const int CH = 4;                    // chunks per plane
    const int F4_PER_PLANE = (V_ * DIN_) / 4;   // 65408
    const int F4_PER_CHUNK = F4_PER_PLANE / CH; // 16352
    const int bx = blockIdx.x;
    const int p = bx / CH, c = bx % CH;
    const float4* __restrict__ src = (const float4*)vu;
    float4* __restrict__ dst = (float4*)hold + (size_t)p * F4_PER_PLANE;
    const int end = (c + 1) * F4_PER_CHUNK;
    for (int k = c * F4_PER_CHUNK + threadIdx.x; k < end; k += 256)
        dst[k] = src[k];
}

// ---------------- kernel 5: overwrite replaced rows in h_old_stack ----------------
// grid = DEPTH*B planes, 128 threads.
__global__ void k_fixrows(const float* __restrict__ sel, const int* __restrict__ idxh_g,
                          float* __restrict__ hold) {
    const int p = blockIdx.x;        // i*B + b
    const int i = p >> 7;            // / 128
    const int b = p & 127;
    const int t = threadIdx.x;
    for (int j = 0; j < i; ++j) {
        int r = idxh_g[b * DEPTH_ + j];
        bool alive = true;
        for (int j2 = j + 1; j2 < i; ++j2)
            if (idxh_g[b * DEPTH_ + j2] == r) { alive = false; break; }
        if (!alive) continue;
        const float* __restrict__ src = sel + (size_t)(j * B_ + b) * DIN_;
        float* __restrict__ dst = hold + ((size_t)p * V_ + r) * DIN_;
        for (int d = t; d < DIN_; d += 128) dst[d] = src[d];
    }
}

extern "C" void kernel_launch(void* const* d_in, const int* in_sizes, int n_in,
                              void* d_out, int out_size, void* d_ws, size_t ws_size,
                              hipStream_t stream) {
    const float* inp    = (const float*)d_in[0];  // (B, DIN)
    const float* vu     = (const float*)d_in[1];  // (V, DIN)
    const float* L      = (const float*)d_in[2];  // (DEPTH, V)
    const float* vfs    = (const float*)d_in[3];  // (V, DOUT)
    const float* biases = (const float*)d_in[4];  // (DEPTH, DOUT)

    float* out   = (float*)d_out;                                  // (B,1,DOUT)
    float* hold  = out + (size_t)B_ * DOUT_;                       // (DEPTH,B,V,DIN)
    float* sel   = hold + (size_t)DEPTH_ * B_ * V_ * DIN_;         // (DEPTH,B,DIN)
    float* lasth = sel + (size_t)DEPTH_ * B_ * DIN_;               // (B,DIN)

    float* W     = (float*)d_ws;                  // DEPTH*V
    float* baseH = W + DEPTH_ * V_;               // DEPTH*DIN
    float* baseF = baseH + DEPTH_ * DIN_;         // DEPTH*DOUT
    int*   idxh  = (int*)(baseF + DEPTH_ * DOUT_);// B*DEPTH

    k_softmax<<<DEPTH_, 256, 0, stream>>>(L, W);
    k_base<<<DEPTH_ * 3, 256, 0, stream>>>(W, vu, vfs, baseH, baseF);
    k_scan<<<B_, 256, 0, stream>>>(inp, vu, vfs, biases, W, baseH, baseF,
                                   out, sel, lasth, idxh);
    k_planes<<<DEPTH_ * B_ * 4, 256, 0, stream>>>(vu, hold);
    k_fixrows<<<DEPTH_ * B_, 128, 0, stream>>>(sel, idxh, hold);
}